// Round 1
// baseline (319.344 us; speedup 1.0000x reference)
//
#include <hip/hip_runtime.h>
#include <cmath>

typedef unsigned short u16;
typedef __bf16 bf16x8 __attribute__((ext_vector_type(8)));
typedef float f32x4 __attribute__((ext_vector_type(4)));

__device__ __forceinline__ u16 f2bf(float f) {
  unsigned u = __float_as_uint(f);
  u += 0x7fffu + ((u >> 16) & 1u);
  return (u16)(u >> 16);
}
__device__ __forceinline__ float bf2f(u16 h) {
  return __uint_as_float(((unsigned)h) << 16);
}
__device__ __forceinline__ f32x4 mfma_bf16(bf16x8 a, bf16x8 b, f32x4 c) {
  return __builtin_amdgcn_mfma_f32_16x16x32_bf16(a, b, c, 0, 0, 0);
}
__device__ __forceinline__ float gelu_exact(float x) {
  return 0.5f * x * (1.0f + erff(x * 0.70710678118654752440f));
}

// B=16, C=128, H=64, W=64, HW=4096, NPOS=65536

// ---------------- pack X: NCHW f32 -> NHWC bf16 ----------------
__global__ __launch_bounds__(256) void pack_x(const float* __restrict__ Fin,
                                              u16* __restrict__ X) {
  const int b = blockIdx.x >> 6, y = blockIdx.x & 63;
  const int tid = threadIdx.x;
  __shared__ float T[64 * 129];
#pragma unroll
  for (int i = 0; i < 32; ++i) {
    int idx = tid + i * 256;
    int c = idx >> 6, x = idx & 63;
    T[x * 129 + c] = Fin[(size_t)(b * 128 + c) * 4096 + y * 64 + x];
  }
  __syncthreads();
#pragma unroll
  for (int i = 0; i < 4; ++i) {
    int chunk = tid + i * 256;  // 1024 chunks of 8 elems
    int x = chunk >> 4;
    int c0 = (chunk & 15) * 8;
    u16 tmp[8];
#pragma unroll
    for (int e = 0; e < 8; ++e) tmp[e] = f2bf(T[x * 129 + c0 + e]);
    *reinterpret_cast<uint4*>(X + ((size_t)((b * 64 + y) * 64 + x) * 128 + c0)) =
        *reinterpret_cast<const uint4*>(tmp);
  }
}

// ---------------- pack weights into B-fragment layout ----------------
// Wpack[conv][step=tap*4+cc][nblk][lane][8]; elem = w[co][ci][dy][dx]
// co = nblk*16 + (lane&15), ci = cc*32 + (lane>>4)*8 + e, tap = dy*3+dx
__global__ __launch_bounds__(256) void pack_w(const float* __restrict__ w0,
                                              const float* __restrict__ w1,
                                              const float* __restrict__ w2,
                                              const float* __restrict__ w3,
                                              const float* __restrict__ w4,
                                              u16* __restrict__ Wpk) {
  int gid = blockIdx.x * 256 + threadIdx.x;  // 92160 total
  int lane = gid & 63;
  int nblk = (gid >> 6) & 7;
  int step = (gid >> 9) % 36;
  int conv = gid / (512 * 36);
  if (conv >= 5) return;
  const float* w = conv == 0 ? w0 : conv == 1 ? w1 : conv == 2 ? w2 : conv == 3 ? w3 : w4;
  int tap = step >> 2, cc = step & 3;
  int dy = tap / 3, dx = tap % 3;
  int co = nblk * 16 + (lane & 15);
  int ci0 = cc * 32 + (lane >> 4) * 8;
  u16 tmp[8];
#pragma unroll
  for (int e = 0; e < 8; ++e)
    tmp[e] = f2bf(w[((size_t)(co * 128 + ci0 + e) * 3 + dy) * 3 + dx]);
  size_t off = ((size_t)conv * 36 * 8 * 64 + (size_t)((step * 8 + nblk) * 64 + lane)) * 8;
  *reinterpret_cast<uint4*>(Wpk + off) = *reinterpret_cast<const uint4*>(tmp);
}

// ---------------- conv3x3 as implicit GEMM ----------------
// MODE 0: natural bf16 out (+bias)            [V]
// MODE 1: natural bf16 out (+bias, gelu)      [hidden]
// MODE 2: transposed bf16 out [b][co][pos]    [QT/KT]
// MODE 3: f32 NCHW out (+bias + Fssm add)     [final]
template <int MODE>
__global__ __launch_bounds__(256, 2) void conv_gemm(
    const u16* __restrict__ Xin, const u16* __restrict__ Wp,
    const float* __restrict__ bias, u16* __restrict__ OutB,
    float* __restrict__ OutF, const u16* __restrict__ Fssm) {
  __shared__ alignas(16) u16 Xs[4 * 66 * 128];  // 67584 B, x-halo, XOR-swizzled
  const int tid = threadIdx.x;
  const int lane = tid & 63;
  const int wv = tid >> 6;
  const int wm = wv >> 1, wn = wv & 1;
  int mt = blockIdx.x;
  mt = (mt & 7) * 64 + (mt >> 3);  // XCD swizzle (512 blocks, bijective)
  const int b = mt >> 5;
  const int y0 = (mt & 31) * 2;

  // ---- stage A once: rows y0-1..y0+2, 64 x (+halo), 128 ci ----
#pragma unroll
  for (int i = 0; i < 16; ++i) {
    int j = tid + i * 256;  // 0..4095 chunks of 16B
    int row = j >> 4;       // ys*64 + x
    int c16 = j & 15;
    int ys = row >> 6, x = row & 63;
    int ysrc = y0 - 1 + ys;
    uint4 val = make_uint4(0u, 0u, 0u, 0u);
    if ((unsigned)ysrc < 64u)
      val = *reinterpret_cast<const uint4*>(
          Xin + ((size_t)((b * 64 + ysrc) * 64 + x) * 128 + c16 * 8));
    int xs = x + 1;
    unsigned off = (unsigned)(((ys * 66 + xs) * 128 + c16 * 8) * 2) ^
                   (unsigned)((xs & 7) << 4);
    *reinterpret_cast<uint4*>(reinterpret_cast<char*>(Xs) + off) = val;
  }
  if (tid < 128) {  // x-halo columns xs=0,65 -> zeros
    int ys = tid >> 5, side = (tid >> 4) & 1, c16 = tid & 15;
    int xs = side ? 65 : 0;
    unsigned off = (unsigned)(((ys * 66 + xs) * 128 + c16 * 8) * 2) ^
                   (unsigned)((xs & 7) << 4);
    *reinterpret_cast<uint4*>(reinterpret_cast<char*>(Xs) + off) =
        make_uint4(0u, 0u, 0u, 0u);
  }
  __syncthreads();

  f32x4 acc[4][4];
#pragma unroll
  for (int i = 0; i < 4; ++i)
#pragma unroll
    for (int j = 0; j < 4; ++j) acc[i][j] = f32x4{0.f, 0.f, 0.f, 0.f};

  const int lm = lane & 15, lq = lane >> 4;
  const u16* wlane = Wp + (size_t)lane * 8;

#pragma unroll
  for (int tap = 0; tap < 9; ++tap) {
    const int dy = tap / 3, dx = tap % 3;
#pragma unroll
    for (int cc = 0; cc < 4; ++cc) {
      const int step = tap * 4 + cc;
      bf16x8 af[4], bfr[4];
#pragma unroll
      for (int i = 0; i < 4; ++i) {
        int pos = wm * 64 + i * 16 + lm;
        int x = pos & 63, yr = pos >> 6;
        int xs = x + dx, ys = yr + dy;
        unsigned off = (unsigned)(((ys * 66 + xs) * 128 + cc * 32 + lq * 8) * 2) ^
                       (unsigned)((xs & 7) << 4);
        af[i] = *reinterpret_cast<const bf16x8*>(
            reinterpret_cast<const char*>(Xs) + off);
      }
#pragma unroll
      for (int j = 0; j < 4; ++j)
        bfr[j] = *reinterpret_cast<const bf16x8*>(
            wlane + (size_t)((step * 8 + wn * 4 + j) * 64) * 8);
#pragma unroll
      for (int i = 0; i < 4; ++i)
#pragma unroll
        for (int j = 0; j < 4; ++j) acc[i][j] = mfma_bf16(af[i], bfr[j], acc[i][j]);
    }
  }

  __syncthreads();  // done reading Xs; reuse for epilogue repack

  if (MODE <= 2) {
    u16* T = Xs;  // [128][136] bf16
#pragma unroll
    for (int i = 0; i < 4; ++i)
#pragma unroll
      for (int j = 0; j < 4; ++j) {
        int n = wn * 64 + j * 16 + lm;
        float bs = bias[n];
#pragma unroll
        for (int r = 0; r < 4; ++r) {
          int m = wm * 64 + i * 16 + lq * 4 + r;
          float v = acc[i][j][r] + bs;
          if (MODE == 1) v = gelu_exact(v);
          if (MODE == 2)
            T[n * 136 + m] = f2bf(v);
          else
            T[m * 136 + n] = f2bf(v);
        }
      }
    __syncthreads();
    int rr = tid >> 1, hf = tid & 1;
    const uint4* src = reinterpret_cast<const uint4*>(T + rr * 136 + hf * 64);
    uint4* dst;
    if (MODE == 2)
      dst = reinterpret_cast<uint4*>(
          OutB + ((size_t)(b * 128 + rr) * 4096 + (mt & 31) * 128 + hf * 64));
    else
      dst = reinterpret_cast<uint4*>(OutB + ((size_t)(mt * 128 + rr) * 128 + hf * 64));
#pragma unroll
    for (int k = 0; k < 8; ++k) dst[k] = src[k];
  } else {
    float* T = reinterpret_cast<float*>(Xs);  // [128][132] f32 = 67584 B
#pragma unroll
    for (int i = 0; i < 4; ++i)
#pragma unroll
      for (int j = 0; j < 4; ++j) {
        int n = wn * 64 + j * 16 + lm;
        float bs = bias[n];
#pragma unroll
        for (int r = 0; r < 4; ++r) {
          int m = wm * 64 + i * 16 + lq * 4 + r;
          float v = acc[i][j][r] + bs + bf2f(Fssm[(size_t)(mt * 128 + m) * 128 + n]);
          T[n * 132 + m] = v;
        }
      }
    __syncthreads();
    int rr = tid >> 1, hf = tid & 1;
    const uint4* src = reinterpret_cast<const uint4*>(T + rr * 132 + hf * 64);
    uint4* dst = reinterpret_cast<uint4*>(
        OutF + ((size_t)(b * 128 + rr) * 4096 + (mt & 31) * 128 + hf * 64));
#pragma unroll
    for (int k = 0; k < 16; ++k) dst[k] = src[k];
  }
}

// ---------------- fused attention: S=K^TQ/64, softmax, M=Pspe@A, pack M ----
__global__ __launch_bounds__(256, 1) void attn_sm(const u16* __restrict__ QT,
                                                  const u16* __restrict__ KT,
                                                  const float* __restrict__ Pspe,
                                                  u16* __restrict__ Mpack) {
  __shared__ float Sf[128 * 129];   // 66048 B
  __shared__ u16 AT[128 * 136];     // 34816 B
  const int b = blockIdx.x;
  const int tid = threadIdx.x;
  const int lane = tid & 63;
  const int wv = tid >> 6, wm = wv >> 1, wn = wv & 1;
  const int lm = lane & 15, lq = lane >> 4;

  f32x4 acc[4][4];
#pragma unroll
  for (int i = 0; i < 4; ++i)
#pragma unroll
    for (int j = 0; j < 4; ++j) acc[i][j] = f32x4{0.f, 0.f, 0.f, 0.f};

  const u16* Ab = KT + (size_t)b * 128 * 4096;
  const u16* Bb = QT + (size_t)b * 128 * 4096;
  for (int ks = 0; ks < 128; ++ks) {
    int k0 = ks * 32 + lq * 8;
    bf16x8 af[4], bfr[4];
#pragma unroll
    for (int i = 0; i < 4; ++i)
      af[i] = *reinterpret_cast<const bf16x8*>(Ab + (size_t)(wm * 64 + i * 16 + lm) * 4096 + k0);
#pragma unroll
    for (int j = 0; j < 4; ++j)
      bfr[j] = *reinterpret_cast<const bf16x8*>(Bb + (size_t)(wn * 64 + j * 16 + lm) * 4096 + k0);
#pragma unroll
    for (int i = 0; i < 4; ++i)
#pragma unroll
      for (int j = 0; j < 4; ++j) acc[i][j] = mfma_bf16(af[i], bfr[j], acc[i][j]);
  }
#pragma unroll
  for (int i = 0; i < 4; ++i)
#pragma unroll
    for (int j = 0; j < 4; ++j)
#pragma unroll
      for (int r = 0; r < 4; ++r)
        Sf[(wm * 64 + i * 16 + lq * 4 + r) * 129 + wn * 64 + j * 16 + lm] =
            acc[i][j][r] * 0.015625f;  // /sqrt(4096)
  __syncthreads();

  // softmax over d per row c; write A^T bf16 into AT[d][c]
  {
    int c = tid >> 1, hf = tid & 1;
    float* row = Sf + c * 129 + hf * 64;
    float mx = -3.4e38f;
#pragma unroll
    for (int k = 0; k < 64; ++k) mx = fmaxf(mx, row[k]);
    mx = fmaxf(mx, __shfl_xor(mx, 1));
    float s = 0.f;
#pragma unroll
    for (int k = 0; k < 64; ++k) {
      float e = __expf(row[k] - mx);
      row[k] = e;
      s += e;
    }
    s += __shfl_xor(s, 1);
    float inv = 1.0f / s;
#pragma unroll
    for (int k = 0; k < 64; ++k) AT[(hf * 64 + k) * 136 + c] = f2bf(row[k] * inv);
  }
  __syncthreads();

  // M = Pspe @ A : A-op P[c][e] (f32->bf16), B-op AT[d][e]
  f32x4 acc2[4][4];
#pragma unroll
  for (int i = 0; i < 4; ++i)
#pragma unroll
    for (int j = 0; j < 4; ++j) acc2[i][j] = f32x4{0.f, 0.f, 0.f, 0.f};
  const float* P = Pspe + (size_t)b * 128 * 128;
#pragma unroll
  for (int cc = 0; cc < 4; ++cc) {
    int e0 = cc * 32 + lq * 8;
    bf16x8 af[4], bfr[4];
#pragma unroll
    for (int i = 0; i < 4; ++i) {
      const float* p = P + (size_t)(wm * 64 + i * 16 + lm) * 128 + e0;
      union { u16 u[8]; bf16x8 v; } cv;
#pragma unroll
      for (int e = 0; e < 8; ++e) cv.u[e] = f2bf(p[e]);
      af[i] = cv.v;
    }
#pragma unroll
    for (int j = 0; j < 4; ++j)
      bfr[j] = *reinterpret_cast<const bf16x8*>(AT + (wn * 64 + j * 16 + lm) * 136 + e0);
#pragma unroll
    for (int i = 0; i < 4; ++i)
#pragma unroll
      for (int j = 0; j < 4; ++j) acc2[i][j] = mfma_bf16(af[i], bfr[j], acc2[i][j]);
  }

  // write M transposed [d][c] into Ml (aliases Sf, dead now)
  u16* Ml = reinterpret_cast<u16*>(Sf);  // [128][136]
#pragma unroll
  for (int i = 0; i < 4; ++i)
#pragma unroll
    for (int j = 0; j < 4; ++j)
#pragma unroll
      for (int r = 0; r < 4; ++r)
        Ml[(wn * 64 + j * 16 + lm) * 136 + (wm * 64 + i * 16 + lq * 4 + r)] =
            f2bf(acc2[i][j][r]);
  __syncthreads();

  // pack M into B-fragment layout: Mpack[b][cc][nblk][lane][8]
#pragma unroll
  for (int it = 0; it < 8; ++it) {
    int item = tid + it * 256;  // 0..2047
    int l2 = item & 63, nb = (item >> 6) & 7, cc2 = item >> 9;
    int d = nb * 16 + (l2 & 15), c0 = cc2 * 32 + (l2 >> 4) * 8;
    *reinterpret_cast<uint4*>(Mpack + (size_t)b * 16384 + (size_t)item * 8) =
        *reinterpret_cast<const uint4*>(Ml + d * 136 + c0);
  }
}

// ---------------- F3 = V @ M -> Fssm (NHWC bf16) ----------------
__global__ __launch_bounds__(256) void f3_gemm(const u16* __restrict__ V,
                                               const u16* __restrict__ Mpack,
                                               u16* __restrict__ Fout) {
  const int tid = threadIdx.x;
  const int lane = tid & 63;
  const int wv = tid >> 6, wm = wv >> 1, wn = wv & 1;
  const int lm = lane & 15, lq = lane >> 4;
  int mt = blockIdx.x;
  mt = (mt & 7) * 64 + (mt >> 3);
  const int b = mt >> 5;

  f32x4 acc[4][4];
#pragma unroll
  for (int i = 0; i < 4; ++i)
#pragma unroll
    for (int j = 0; j < 4; ++j) acc[i][j] = f32x4{0.f, 0.f, 0.f, 0.f};

#pragma unroll
  for (int cc = 0; cc < 4; ++cc) {
    int k0 = cc * 32 + lq * 8;
    bf16x8 af[4], bfr[4];
#pragma unroll
    for (int i = 0; i < 4; ++i)
      af[i] = *reinterpret_cast<const bf16x8*>(
          V + (size_t)(mt * 128 + wm * 64 + i * 16 + lm) * 128 + k0);
#pragma unroll
    for (int j = 0; j < 4; ++j)
      bfr[j] = *reinterpret_cast<const bf16x8*>(
          Mpack + (size_t)b * 16384 + (size_t)((cc * 8 + wn * 4 + j) * 64 + lane) * 8);
#pragma unroll
    for (int i = 0; i < 4; ++i)
#pragma unroll
      for (int j = 0; j < 4; ++j) acc[i][j] = mfma_bf16(af[i], bfr[j], acc[i][j]);
  }

  __shared__ u16 T[128 * 136];
#pragma unroll
  for (int i = 0; i < 4; ++i)
#pragma unroll
    for (int j = 0; j < 4; ++j)
#pragma unroll
      for (int r = 0; r < 4; ++r)
        T[(wm * 64 + i * 16 + lq * 4 + r) * 136 + wn * 64 + j * 16 + lm] =
            f2bf(acc[i][j][r]);
  __syncthreads();
  int rr = tid >> 1, hf = tid & 1;
  const uint4* src = reinterpret_cast<const uint4*>(T + rr * 136 + hf * 64);
  uint4* dst = reinterpret_cast<uint4*>(Fout + ((size_t)(mt * 128 + rr) * 128 + hf * 64));
#pragma unroll
  for (int k = 0; k < 8; ++k) dst[k] = src[k];
}

extern "C" void kernel_launch(void* const* d_in, const int* in_sizes, int n_in,
                              void* d_out, int out_size, void* d_ws, size_t ws_size,
                              hipStream_t stream) {
  const float* F_in = (const float*)d_in[0];
  const float* Pspe = (const float*)d_in[1];
  const float* q_w = (const float*)d_in[2];
  const float* q_b = (const float*)d_in[3];
  const float* k_w = (const float*)d_in[4];
  const float* k_b = (const float*)d_in[5];
  const float* v_w = (const float*)d_in[6];
  const float* v_b = (const float*)d_in[7];
  const float* f1_w = (const float*)d_in[8];
  const float* f1_b = (const float*)d_in[9];
  const float* f2_w = (const float*)d_in[10];
  const float* f2_b = (const float*)d_in[11];
  float* out = (float*)d_out;

  char* ws = (char*)d_ws;
  const size_t SZ = 16777216;  // 65536*128*2 bytes
  u16* X = (u16*)(ws);               // NHWC bf16 input; later reused as Fssm
  u16* QT = (u16*)(ws + SZ);         // [b][c][hw]; later reused as hidden
  u16* KT = (u16*)(ws + 2 * SZ);
  u16* V = (u16*)(ws + 3 * SZ);
  u16* Wpk = (u16*)(ws + 4 * SZ);                 // 5*36*8*64*8*2 = 1474560 B
  u16* Mpk = (u16*)(ws + 4 * SZ + 1474560);       // 16*16384*2 = 524288 B
  u16* Fssm = X;
  u16* Hid = QT;

  pack_x<<<1024, 256, 0, stream>>>(F_in, X);
  pack_w<<<360, 256, 0, stream>>>(q_w, k_w, v_w, f1_w, f2_w, Wpk);
  conv_gemm<2><<<512, 256, 0, stream>>>(X, Wpk, q_b, QT, nullptr, nullptr);
  conv_gemm<2><<<512, 256, 0, stream>>>(X, Wpk + 147456, k_b, KT, nullptr, nullptr);
  conv_gemm<0><<<512, 256, 0, stream>>>(X, Wpk + 2 * 147456, v_b, V, nullptr, nullptr);
  attn_sm<<<16, 256, 0, stream>>>(QT, KT, Pspe, Mpk);
  f3_gemm<<<512, 256, 0, stream>>>(V, Mpk, Fssm);
  conv_gemm<1><<<512, 256, 0, stream>>>(Fssm, Wpk + 3 * 147456, f1_b, Hid, nullptr, nullptr);
  conv_gemm<3><<<512, 256, 0, stream>>>(Hid, Wpk + 4 * 147456, f2_b, nullptr, out, Fssm);
}

// Round 2
// 199.677 us; speedup vs baseline: 1.5993x; 1.5993x over previous
//
#include <hip/hip_runtime.h>
#include <cmath>

typedef unsigned short u16;
typedef __bf16 bf16x8 __attribute__((ext_vector_type(8)));
typedef float f32x4 __attribute__((ext_vector_type(4)));

__device__ __forceinline__ u16 f2bf(float f) {
  unsigned u = __float_as_uint(f);
  u += 0x7fffu + ((u >> 16) & 1u);
  return (u16)(u >> 16);
}
__device__ __forceinline__ float bf2f(u16 h) {
  return __uint_as_float(((unsigned)h) << 16);
}
__device__ __forceinline__ f32x4 mfma_bf16(bf16x8 a, bf16x8 b, f32x4 c) {
  return __builtin_amdgcn_mfma_f32_16x16x32_bf16(a, b, c, 0, 0, 0);
}
__device__ __forceinline__ float gelu_exact(float x) {
  return 0.5f * x * (1.0f + erff(x * 0.70710678118654752440f));
}

// B=16, C=128, H=64, W=64, HW=4096, NPOS=65536

// ---------------- pack X: NCHW f32 -> NHWC bf16 ----------------
__global__ __launch_bounds__(256) void pack_x(const float* __restrict__ Fin,
                                              u16* __restrict__ X) {
  const int b = blockIdx.x >> 6, y = blockIdx.x & 63;
  const int tid = threadIdx.x;
  __shared__ float T[64 * 129];
#pragma unroll
  for (int i = 0; i < 32; ++i) {
    int idx = tid + i * 256;
    int c = idx >> 6, x = idx & 63;
    T[x * 129 + c] = Fin[(size_t)(b * 128 + c) * 4096 + y * 64 + x];
  }
  __syncthreads();
#pragma unroll
  for (int i = 0; i < 4; ++i) {
    int chunk = tid + i * 256;  // 1024 chunks of 8 elems
    int x = chunk >> 4;
    int c0 = (chunk & 15) * 8;
    u16 tmp[8];
#pragma unroll
    for (int e = 0; e < 8; ++e) tmp[e] = f2bf(T[x * 129 + c0 + e]);
    *reinterpret_cast<uint4*>(X + ((size_t)((b * 64 + y) * 64 + x) * 128 + c0)) =
        *reinterpret_cast<const uint4*>(tmp);
  }
}

// ---------------- pack weights into B-fragment layout ----------------
__global__ __launch_bounds__(256) void pack_w(const float* __restrict__ w0,
                                              const float* __restrict__ w1,
                                              const float* __restrict__ w2,
                                              const float* __restrict__ w3,
                                              const float* __restrict__ w4,
                                              u16* __restrict__ Wpk) {
  int gid = blockIdx.x * 256 + threadIdx.x;  // 92160 total
  int lane = gid & 63;
  int nblk = (gid >> 6) & 7;
  int step = (gid >> 9) % 36;
  int conv = gid / (512 * 36);
  if (conv >= 5) return;
  const float* w = conv == 0 ? w0 : conv == 1 ? w1 : conv == 2 ? w2 : conv == 3 ? w3 : w4;
  int tap = step >> 2, cc = step & 3;
  int dy = tap / 3, dx = tap % 3;
  int co = nblk * 16 + (lane & 15);
  int ci0 = cc * 32 + (lane >> 4) * 8;
  u16 tmp[8];
#pragma unroll
  for (int e = 0; e < 8; ++e)
    tmp[e] = f2bf(w[((size_t)(co * 128 + ci0 + e) * 3 + dy) * 3 + dx]);
  size_t off = ((size_t)conv * 36 * 8 * 64 + (size_t)((step * 8 + nblk) * 64 + lane)) * 8;
  *reinterpret_cast<uint4*>(Wpk + off) = *reinterpret_cast<const uint4*>(tmp);
}

// ---------------- conv3x3 as implicit GEMM ----------------
// MODE 0: natural bf16 out (+bias)                      [V]
// MODE 1: natural bf16 out (+bias, gelu)                [hidden]
// MODE 2: fragment-packed bf16 out PK[b][ks][cb][l][8]  [QP/KP]
// MODE 3: f32 NCHW out (+bias + Fssm add)               [final]
template <int MODE>
__global__ __launch_bounds__(256, 2) void conv_gemm(
    const u16* __restrict__ Xin, const u16* __restrict__ Wp,
    const float* __restrict__ bias, u16* __restrict__ OutB,
    float* __restrict__ OutF, const u16* __restrict__ Fssm) {
  __shared__ alignas(16) u16 Xs[4 * 66 * 128];  // 67584 B, x-halo, XOR-swizzled
  const int tid = threadIdx.x;
  const int lane = tid & 63;
  const int wv = tid >> 6;
  const int wm = wv >> 1, wn = wv & 1;
  int mt = blockIdx.x;
  mt = (mt & 7) * 64 + (mt >> 3);  // XCD swizzle (512 blocks, bijective)
  const int b = mt >> 5;
  const int y0 = (mt & 31) * 2;

  // ---- stage A once: rows y0-1..y0+2, 64 x (+halo), 128 ci ----
#pragma unroll
  for (int i = 0; i < 16; ++i) {
    int j = tid + i * 256;  // 0..4095 chunks of 16B
    int row = j >> 4;       // ys*64 + x
    int c16 = j & 15;
    int ys = row >> 6, x = row & 63;
    int ysrc = y0 - 1 + ys;
    uint4 val = make_uint4(0u, 0u, 0u, 0u);
    if ((unsigned)ysrc < 64u)
      val = *reinterpret_cast<const uint4*>(
          Xin + ((size_t)((b * 64 + ysrc) * 64 + x) * 128 + c16 * 8));
    int xs = x + 1;
    unsigned off = (unsigned)(((ys * 66 + xs) * 128 + c16 * 8) * 2) ^
                   (unsigned)((xs & 7) << 4);
    *reinterpret_cast<uint4*>(reinterpret_cast<char*>(Xs) + off) = val;
  }
  if (tid < 128) {  // x-halo columns xs=0,65 -> zeros
    int ys = tid >> 5, side = (tid >> 4) & 1, c16 = tid & 15;
    int xs = side ? 65 : 0;
    unsigned off = (unsigned)(((ys * 66 + xs) * 128 + c16 * 8) * 2) ^
                   (unsigned)((xs & 7) << 4);
    *reinterpret_cast<uint4*>(reinterpret_cast<char*>(Xs) + off) =
        make_uint4(0u, 0u, 0u, 0u);
  }
  __syncthreads();

  f32x4 acc[4][4];
#pragma unroll
  for (int i = 0; i < 4; ++i)
#pragma unroll
    for (int j = 0; j < 4; ++j) acc[i][j] = f32x4{0.f, 0.f, 0.f, 0.f};

  const int lm = lane & 15, lq = lane >> 4;
  const u16* wlane = Wp + (size_t)lane * 8;

#pragma unroll
  for (int tap = 0; tap < 9; ++tap) {
    const int dy = tap / 3, dx = tap % 3;
#pragma unroll
    for (int cc = 0; cc < 4; ++cc) {
      const int step = tap * 4 + cc;
      bf16x8 af[4], bfr[4];
#pragma unroll
      for (int i = 0; i < 4; ++i) {
        int pos = wm * 64 + i * 16 + lm;
        int x = pos & 63, yr = pos >> 6;
        int xs = x + dx, ys = yr + dy;
        unsigned off = (unsigned)(((ys * 66 + xs) * 128 + cc * 32 + lq * 8) * 2) ^
                       (unsigned)((xs & 7) << 4);
        af[i] = *reinterpret_cast<const bf16x8*>(
            reinterpret_cast<const char*>(Xs) + off);
      }
#pragma unroll
      for (int j = 0; j < 4; ++j)
        bfr[j] = *reinterpret_cast<const bf16x8*>(
            wlane + (size_t)((step * 8 + wn * 4 + j) * 64) * 8);
#pragma unroll
      for (int i = 0; i < 4; ++i)
#pragma unroll
        for (int j = 0; j < 4; ++j) acc[i][j] = mfma_bf16(af[i], bfr[j], acc[i][j]);
    }
  }

  __syncthreads();  // done reading Xs; reuse for epilogue repack

  if (MODE <= 2) {
    u16* T = Xs;  // [128][136] bf16
#pragma unroll
    for (int i = 0; i < 4; ++i)
#pragma unroll
      for (int j = 0; j < 4; ++j) {
        int n = wn * 64 + j * 16 + lm;
        float bs = bias[n];
#pragma unroll
        for (int r = 0; r < 4; ++r) {
          int m = wm * 64 + i * 16 + lq * 4 + r;
          float v = acc[i][j][r] + bs;
          if (MODE == 1) v = gelu_exact(v);
          if (MODE == 2)
            T[n * 136 + m] = f2bf(v);
          else
            T[m * 136 + n] = f2bf(v);
        }
      }
    __syncthreads();
    if (MODE == 2) {
      // pack into PK[b][ks][cb][lane][8]; elem = ch[cb*16+(l&15)], pos = ks*32+(l>>4)*8+e
      const int ksbase = (mt & 31) * 4;
#pragma unroll
      for (int it = 0; it < 8; ++it) {
        int item = tid + it * 256;  // 0..2047
        int l = item & 63, cb = (item >> 6) & 7, ksl = item >> 9;
        int c = cb * 16 + (l & 15);
        int mloc = ksl * 32 + (l >> 4) * 8;
        *reinterpret_cast<uint4*>(
            OutB + (size_t)(((b * 128 + ksbase + ksl) * 8 + cb) * 64 + l) * 8) =
            *reinterpret_cast<const uint4*>(T + c * 136 + mloc);
      }
    } else {
      int rr = tid >> 1, hf = tid & 1;
      const uint4* src = reinterpret_cast<const uint4*>(T + rr * 136 + hf * 64);
      uint4* dst = reinterpret_cast<uint4*>(OutB + ((size_t)(mt * 128 + rr) * 128 + hf * 64));
#pragma unroll
      for (int k = 0; k < 8; ++k) dst[k] = src[k];
    }
  } else {
    float* T = reinterpret_cast<float*>(Xs);  // [128][132] f32 = 67584 B
#pragma unroll
    for (int i = 0; i < 4; ++i)
#pragma unroll
      for (int j = 0; j < 4; ++j) {
        int n = wn * 64 + j * 16 + lm;
        float bs = bias[n];
#pragma unroll
        for (int r = 0; r < 4; ++r) {
          int m = wm * 64 + i * 16 + lq * 4 + r;
          float v = acc[i][j][r] + bs + bf2f(Fssm[(size_t)(mt * 128 + m) * 128 + n]);
          T[n * 132 + m] = v;
        }
      }
    __syncthreads();
    int rr = tid >> 1, hf = tid & 1;
    const uint4* src = reinterpret_cast<const uint4*>(T + rr * 132 + hf * 64);
    uint4* dst = reinterpret_cast<uint4*>(
        OutF + ((size_t)(b * 128 + rr) * 4096 + (mt & 31) * 128 + hf * 64));
#pragma unroll
    for (int k = 0; k < 16; ++k) dst[k] = src[k];
  }
}

// ---------------- S = K^T Q, split-K=16 -> f32 partials ----------------
__global__ __launch_bounds__(256, 2) void attn_s(const u16* __restrict__ QP,
                                                 const u16* __restrict__ KP,
                                                 float* __restrict__ SP) {
  const int tid = threadIdx.x;
  const int lane = tid & 63;
  const int wv = tid >> 6, wm = wv >> 1, wn = wv & 1;
  const int lm = lane & 15, lq = lane >> 4;
  int mt = blockIdx.x;
  mt = (mt & 7) * 32 + (mt >> 3);  // 256 blocks, bijective XCD swizzle
  const int b = mt >> 4, sp = mt & 15;

  f32x4 acc[4][4];
#pragma unroll
  for (int i = 0; i < 4; ++i)
#pragma unroll
    for (int j = 0; j < 4; ++j) acc[i][j] = f32x4{0.f, 0.f, 0.f, 0.f};

#pragma unroll
  for (int ksl = 0; ksl < 8; ++ksl) {
    const int ks = sp * 8 + ksl;
    bf16x8 af[4], bfr[4];
#pragma unroll
    for (int i = 0; i < 4; ++i)
      af[i] = *reinterpret_cast<const bf16x8*>(
          KP + (size_t)(((b * 128 + ks) * 8 + wm * 4 + i) * 64 + lane) * 8);
#pragma unroll
    for (int j = 0; j < 4; ++j)
      bfr[j] = *reinterpret_cast<const bf16x8*>(
          QP + (size_t)(((b * 128 + ks) * 8 + wn * 4 + j) * 64 + lane) * 8);
#pragma unroll
    for (int i = 0; i < 4; ++i)
#pragma unroll
      for (int j = 0; j < 4; ++j) acc[i][j] = mfma_bf16(af[i], bfr[j], acc[i][j]);
  }

  float* out = SP + (size_t)(b * 16 + sp) * 16384;
#pragma unroll
  for (int i = 0; i < 4; ++i)
#pragma unroll
    for (int j = 0; j < 4; ++j)
#pragma unroll
      for (int r = 0; r < 4; ++r)
        out[(wm * 64 + i * 16 + lq * 4 + r) * 128 + wn * 64 + j * 16 + lm] =
            acc[i][j][r];
}

// ---------------- reduce partials + softmax + pack A ----------------
// grid 64 = b*4 + eb; block handles S rows [eb*32, eb*32+32)
__global__ __launch_bounds__(256) void attn_r(const float* __restrict__ SP,
                                              u16* __restrict__ ABP) {
  __shared__ float Sf[32][129];
  __shared__ float Inv[32];
  const int tid = threadIdx.x;
  const int b = blockIdx.x >> 2, eb = blockIdx.x & 3;

  // reduce 16 partials: 4096 outputs, 16/thread, coalesced over d
#pragma unroll
  for (int it = 0; it < 16; ++it) {
    int id = it * 256 + tid;
    int rl = id >> 7, d = id & 127;
    const float* p = SP + (size_t)b * 16 * 16384 + (size_t)(eb * 32 + rl) * 128 + d;
    float s = 0.f;
#pragma unroll
    for (int sp = 0; sp < 16; ++sp) s += p[(size_t)sp * 16384];
    Sf[rl][d] = s * 0.015625f;  // /sqrt(4096)
  }
  __syncthreads();

  // softmax per row: 8 lanes/row
  {
    int rl = tid >> 3, sub = tid & 7;
    float mx = -3.4e38f;
#pragma unroll
    for (int k = 0; k < 16; ++k) mx = fmaxf(mx, Sf[rl][sub + 8 * k]);
    mx = fmaxf(mx, __shfl_xor(mx, 1));
    mx = fmaxf(mx, __shfl_xor(mx, 2));
    mx = fmaxf(mx, __shfl_xor(mx, 4));
    float s = 0.f;
#pragma unroll
    for (int k = 0; k < 16; ++k) {
      float e = __expf(Sf[rl][sub + 8 * k] - mx);
      Sf[rl][sub + 8 * k] = e;
      s += e;
    }
    s += __shfl_xor(s, 1);
    s += __shfl_xor(s, 2);
    s += __shfl_xor(s, 4);
    if (sub == 0) Inv[rl] = 1.0f / s;
  }
  __syncthreads();

  // pack A into B-frag layout ABP[b][ks=eb][nb][l][8]:
  // elem = A[e = eb*32+(l>>4)*8+e'][d = nb*16+(l&15)]
#pragma unroll
  for (int it = 0; it < 2; ++it) {
    int item = tid + it * 256;  // 0..511
    int l = item & 63, nb = item >> 6;
    int d = nb * 16 + (l & 15);
    u16 tmp[8];
#pragma unroll
    for (int e = 0; e < 8; ++e) {
      int rloc = (l >> 4) * 8 + e;
      tmp[e] = f2bf(Sf[rloc][d] * Inv[rloc]);
    }
    *reinterpret_cast<uint4*>(ABP + (size_t)(((b * 4 + eb) * 8 + nb) * 64 + l) * 8) =
        *reinterpret_cast<const uint4*>(tmp);
  }
}

// ---------------- M = Pspe @ A, pack M ----------------
__global__ __launch_bounds__(256, 1) void attn_m(const float* __restrict__ Pspe,
                                                 const u16* __restrict__ ABP,
                                                 u16* __restrict__ Mpack) {
  __shared__ u16 Ml[128 * 136];
  const int b = blockIdx.x;
  const int tid = threadIdx.x;
  const int lane = tid & 63;
  const int wv = tid >> 6, wm = wv >> 1, wn = wv & 1;
  const int lm = lane & 15, lq = lane >> 4;

  f32x4 acc[4][4];
#pragma unroll
  for (int i = 0; i < 4; ++i)
#pragma unroll
    for (int j = 0; j < 4; ++j) acc[i][j] = f32x4{0.f, 0.f, 0.f, 0.f};

  const float* P = Pspe + (size_t)b * 128 * 128;
#pragma unroll
  for (int cc = 0; cc < 4; ++cc) {
    int e0 = cc * 32 + lq * 8;
    bf16x8 af[4], bfr[4];
#pragma unroll
    for (int i = 0; i < 4; ++i) {
      const float* p = P + (size_t)(wm * 64 + i * 16 + lm) * 128 + e0;
      union { u16 u[8]; bf16x8 v; } cv;
#pragma unroll
      for (int e = 0; e < 8; ++e) cv.u[e] = f2bf(p[e]);
      af[i] = cv.v;
    }
#pragma unroll
    for (int j = 0; j < 4; ++j)
      bfr[j] = *reinterpret_cast<const bf16x8*>(
          ABP + (size_t)(((b * 4 + cc) * 8 + wn * 4 + j) * 64 + lane) * 8);
#pragma unroll
    for (int i = 0; i < 4; ++i)
#pragma unroll
      for (int j = 0; j < 4; ++j) acc[i][j] = mfma_bf16(af[i], bfr[j], acc[i][j]);
  }

  // write M transposed [d][c] then pack
#pragma unroll
  for (int i = 0; i < 4; ++i)
#pragma unroll
    for (int j = 0; j < 4; ++j)
#pragma unroll
      for (int r = 0; r < 4; ++r)
        Ml[(wn * 64 + j * 16 + lm) * 136 + (wm * 64 + i * 16 + lq * 4 + r)] =
            f2bf(acc[i][j][r]);
  __syncthreads();

#pragma unroll
  for (int it = 0; it < 8; ++it) {
    int item = tid + it * 256;  // 0..2047
    int l2 = item & 63, nb = (item >> 6) & 7, cc2 = item >> 9;
    int d = nb * 16 + (l2 & 15), c0 = cc2 * 32 + (l2 >> 4) * 8;
    *reinterpret_cast<uint4*>(Mpack + (size_t)b * 16384 + (size_t)item * 8) =
        *reinterpret_cast<const uint4*>(Ml + d * 136 + c0);
  }
}

// ---------------- F3 = V @ M -> Fssm (NHWC bf16) ----------------
__global__ __launch_bounds__(256) void f3_gemm(const u16* __restrict__ V,
                                               const u16* __restrict__ Mpack,
                                               u16* __restrict__ Fout) {
  const int tid = threadIdx.x;
  const int lane = tid & 63;
  const int wv = tid >> 6, wm = wv >> 1, wn = wv & 1;
  const int lm = lane & 15, lq = lane >> 4;
  int mt = blockIdx.x;
  mt = (mt & 7) * 64 + (mt >> 3);
  const int b = mt >> 5;

  f32x4 acc[4][4];
#pragma unroll
  for (int i = 0; i < 4; ++i)
#pragma unroll
    for (int j = 0; j < 4; ++j) acc[i][j] = f32x4{0.f, 0.f, 0.f, 0.f};

#pragma unroll
  for (int cc = 0; cc < 4; ++cc) {
    int k0 = cc * 32 + lq * 8;
    bf16x8 af[4], bfr[4];
#pragma unroll
    for (int i = 0; i < 4; ++i)
      af[i] = *reinterpret_cast<const bf16x8*>(
          V + (size_t)(mt * 128 + wm * 64 + i * 16 + lm) * 128 + k0);
#pragma unroll
    for (int j = 0; j < 4; ++j)
      bfr[j] = *reinterpret_cast<const bf16x8*>(
          Mpack + (size_t)b * 16384 + (size_t)((cc * 8 + wn * 4 + j) * 64 + lane) * 8);
#pragma unroll
    for (int i = 0; i < 4; ++i)
#pragma unroll
      for (int j = 0; j < 4; ++j) acc[i][j] = mfma_bf16(af[i], bfr[j], acc[i][j]);
  }

  __shared__ u16 T[128 * 136];
#pragma unroll
  for (int i = 0; i < 4; ++i)
#pragma unroll
    for (int j = 0; j < 4; ++j)
#pragma unroll
      for (int r = 0; r < 4; ++r)
        T[(wm * 64 + i * 16 + lq * 4 + r) * 136 + wn * 64 + j * 16 + lm] =
            f2bf(acc[i][j][r]);
  __syncthreads();
  int rr = tid >> 1, hf = tid & 1;
  const uint4* src = reinterpret_cast<const uint4*>(T + rr * 136 + hf * 64);
  uint4* dst = reinterpret_cast<uint4*>(Fout + ((size_t)(mt * 128 + rr) * 128 + hf * 64));
#pragma unroll
  for (int k = 0; k < 8; ++k) dst[k] = src[k];
}

extern "C" void kernel_launch(void* const* d_in, const int* in_sizes, int n_in,
                              void* d_out, int out_size, void* d_ws, size_t ws_size,
                              hipStream_t stream) {
  const float* F_in = (const float*)d_in[0];
  const float* Pspe = (const float*)d_in[1];
  const float* q_w = (const float*)d_in[2];
  const float* q_b = (const float*)d_in[3];
  const float* k_w = (const float*)d_in[4];
  const float* k_b = (const float*)d_in[5];
  const float* v_w = (const float*)d_in[6];
  const float* v_b = (const float*)d_in[7];
  const float* f1_w = (const float*)d_in[8];
  const float* f1_b = (const float*)d_in[9];
  const float* f2_w = (const float*)d_in[10];
  const float* f2_b = (const float*)d_in[11];
  float* out = (float*)d_out;

  char* ws = (char*)d_ws;
  const size_t SZ = 16777216;  // 65536*128*2 bytes
  u16* X = (u16*)(ws);                  // NHWC bf16 input
  u16* QP = (u16*)(ws + SZ);            // fragment-packed Q; later reused as hidden
  u16* KP = (u16*)(ws + 2 * SZ);        // fragment-packed K; later reused for ABP
  u16* V = (u16*)(ws + 3 * SZ);
  u16* Wpk = (u16*)(ws + 4 * SZ);                 // 1474560 B
  u16* Mpk = (u16*)(ws + 4 * SZ + 1474560);       // 524288 B
  float* SP = (float*)ws;               // 16 MB f32 partials — aliases X (X dead by then)
  u16* ABP = KP;                        // 512 KB — aliases KP (dead after attn_s)
  u16* Fssm = X;                        // f3 output — aliases X/SP (SP dead by then)
  u16* Hid = QP;

  pack_x<<<1024, 256, 0, stream>>>(F_in, X);
  pack_w<<<360, 256, 0, stream>>>(q_w, k_w, v_w, f1_w, f2_w, Wpk);
  conv_gemm<2><<<512, 256, 0, stream>>>(X, Wpk, q_b, QP, nullptr, nullptr);
  conv_gemm<2><<<512, 256, 0, stream>>>(X, Wpk + 147456, k_b, KP, nullptr, nullptr);
  conv_gemm<0><<<512, 256, 0, stream>>>(X, Wpk + 2 * 147456, v_b, V, nullptr, nullptr);
  attn_s<<<256, 256, 0, stream>>>(QP, KP, SP);
  attn_r<<<64, 256, 0, stream>>>(SP, ABP);
  attn_m<<<16, 256, 0, stream>>>(Pspe, ABP, Mpk);
  f3_gemm<<<512, 256, 0, stream>>>(V, Mpk, Fssm);
  conv_gemm<1><<<512, 256, 0, stream>>>(Fssm, Wpk + 3 * 147456, f1_b, Hid, nullptr, nullptr);
  conv_gemm<3><<<512, 256, 0, stream>>>(Hid, Wpk + 4 * 147456, f2_b, nullptr, out, Fssm);
}

// Round 3
// 182.357 us; speedup vs baseline: 1.7512x; 1.0950x over previous
//
#include <hip/hip_runtime.h>
#include <cmath>

typedef unsigned short u16;
typedef __bf16 bf16x8 __attribute__((ext_vector_type(8)));
typedef float f32x4 __attribute__((ext_vector_type(4)));

__device__ __forceinline__ u16 f2bf(float f) {
  unsigned u = __float_as_uint(f);
  u += 0x7fffu + ((u >> 16) & 1u);
  return (u16)(u >> 16);
}
__device__ __forceinline__ float bf2f(u16 h) {
  return __uint_as_float(((unsigned)h) << 16);
}
__device__ __forceinline__ f32x4 mfma_bf16(bf16x8 a, bf16x8 b, f32x4 c) {
  return __builtin_amdgcn_mfma_f32_16x16x32_bf16(a, b, c, 0, 0, 0);
}
__device__ __forceinline__ float gelu_exact(float x) {
  return 0.5f * x * (1.0f + erff(x * 0.70710678118654752440f));
}

// B=16, C=128, H=64, W=64, HW=4096, NPOS=65536

// ---------------- pack X: NCHW f32 -> NHWC bf16 ----------------
__global__ __launch_bounds__(256) void pack_x(const float* __restrict__ Fin,
                                              u16* __restrict__ X) {
  const int b = blockIdx.x >> 6, y = blockIdx.x & 63;
  const int tid = threadIdx.x;
  __shared__ float T[64 * 129];
#pragma unroll
  for (int i = 0; i < 32; ++i) {
    int idx = tid + i * 256;
    int c = idx >> 6, x = idx & 63;
    T[x * 129 + c] = Fin[(size_t)(b * 128 + c) * 4096 + y * 64 + x];
  }
  __syncthreads();
#pragma unroll
  for (int i = 0; i < 4; ++i) {
    int chunk = tid + i * 256;
    int x = chunk >> 4;
    int c0 = (chunk & 15) * 8;
    u16 tmp[8];
#pragma unroll
    for (int e = 0; e < 8; ++e) tmp[e] = f2bf(T[x * 129 + c0 + e]);
    *reinterpret_cast<uint4*>(X + ((size_t)((b * 64 + y) * 64 + x) * 128 + c0)) =
        *reinterpret_cast<const uint4*>(tmp);
  }
}

// ---------------- pack weights into B-fragment layout ----------------
__global__ __launch_bounds__(256) void pack_w(const float* __restrict__ w0,
                                              const float* __restrict__ w1,
                                              const float* __restrict__ w2,
                                              const float* __restrict__ w3,
                                              const float* __restrict__ w4,
                                              u16* __restrict__ Wpk) {
  int gid = blockIdx.x * 256 + threadIdx.x;
  int lane = gid & 63;
  int nblk = (gid >> 6) & 7;
  int step = (gid >> 9) % 36;
  int conv = gid / (512 * 36);
  if (conv >= 5) return;
  const float* w = conv == 0 ? w0 : conv == 1 ? w1 : conv == 2 ? w2 : conv == 3 ? w3 : w4;
  int tap = step >> 2, cc = step & 3;
  int dy = tap / 3, dx = tap % 3;
  int co = nblk * 16 + (lane & 15);
  int ci0 = cc * 32 + (lane >> 4) * 8;
  u16 tmp[8];
#pragma unroll
  for (int e = 0; e < 8; ++e)
    tmp[e] = f2bf(w[((size_t)(co * 128 + ci0 + e) * 3 + dy) * 3 + dx]);
  size_t off = ((size_t)conv * 36 * 8 * 64 + (size_t)((step * 8 + nblk) * 64 + lane)) * 8;
  *reinterpret_cast<uint4*>(Wpk + off) = *reinterpret_cast<const uint4*>(tmp);
}

// ======== shared staging: rows y0-1..y0+2, x-halo, XOR-swizzled ========
__device__ __forceinline__ void stage_tile(const u16* __restrict__ Xin, u16* Xs,
                                           int tid, int b, int y0) {
#pragma unroll
  for (int i = 0; i < 16; ++i) {
    int j = tid + i * 256;
    int row = j >> 4;
    int c16 = j & 15;
    int ys = row >> 6, x = row & 63;
    int ysrc = y0 - 1 + ys;
    uint4 val = make_uint4(0u, 0u, 0u, 0u);
    if ((unsigned)ysrc < 64u)
      val = *reinterpret_cast<const uint4*>(
          Xin + ((size_t)((b * 64 + ysrc) * 64 + x) * 128 + c16 * 8));
    int xs = x + 1;
    unsigned off = (unsigned)(((ys * 66 + xs) * 128 + c16 * 8) * 2) ^
                   (unsigned)((xs & 7) << 4);
    *reinterpret_cast<uint4*>(reinterpret_cast<char*>(Xs) + off) = val;
  }
  if (tid < 128) {
    int ys = tid >> 5, side = (tid >> 4) & 1, c16 = tid & 15;
    int xs = side ? 65 : 0;
    unsigned off = (unsigned)(((ys * 66 + xs) * 128 + c16 * 8) * 2) ^
                   (unsigned)((xs & 7) << 4);
    *reinterpret_cast<uint4*>(reinterpret_cast<char*>(Xs) + off) =
        make_uint4(0u, 0u, 0u, 0u);
  }
}

// epilogue: fragment-packed output PK[b][ks][cb][lane][8] (Q/K)
__device__ __forceinline__ void epi_pack(f32x4 (&acc)[4][4], const float* __restrict__ bias,
                                         u16* __restrict__ OutB, u16* T, int tid,
                                         int wm, int wn, int lm, int lq, int b, int mt) {
#pragma unroll
  for (int i = 0; i < 4; ++i)
#pragma unroll
    for (int j = 0; j < 4; ++j) {
      int n = wn * 64 + j * 16 + lm;
      float bs = bias[n];
#pragma unroll
      for (int r = 0; r < 4; ++r) {
        int m = wm * 64 + i * 16 + lq * 4 + r;
        T[n * 136 + m] = f2bf(acc[i][j][r] + bs);
      }
    }
  __syncthreads();
  const int ksbase = (mt & 31) * 4;
#pragma unroll
  for (int it = 0; it < 8; ++it) {
    int item = tid + it * 256;
    int l = item & 63, cb = (item >> 6) & 7, ksl = item >> 9;
    int c = cb * 16 + (l & 15);
    int mloc = ksl * 32 + (l >> 4) * 8;
    *reinterpret_cast<uint4*>(
        OutB + (size_t)(((b * 128 + ksbase + ksl) * 8 + cb) * 64 + l) * 8) =
        *reinterpret_cast<const uint4*>(T + c * 136 + mloc);
  }
  __syncthreads();
}

// epilogue: natural [pos][ch] bf16 (V)
__device__ __forceinline__ void epi_nat(f32x4 (&acc)[4][4], const float* __restrict__ bias,
                                        u16* __restrict__ OutB, u16* T, int tid,
                                        int wm, int wn, int lm, int lq, int mt) {
#pragma unroll
  for (int i = 0; i < 4; ++i)
#pragma unroll
    for (int j = 0; j < 4; ++j) {
      int n = wn * 64 + j * 16 + lm;
      float bs = bias[n];
#pragma unroll
      for (int r = 0; r < 4; ++r) {
        int m = wm * 64 + i * 16 + lq * 4 + r;
        T[m * 136 + n] = f2bf(acc[i][j][r] + bs);
      }
    }
  __syncthreads();
  int rr = tid >> 1, hf = tid & 1;
  const uint4* src = reinterpret_cast<const uint4*>(T + rr * 136 + hf * 64);
  uint4* dst = reinterpret_cast<uint4*>(OutB + ((size_t)(mt * 128 + rr) * 128 + hf * 64));
#pragma unroll
  for (int k = 0; k < 8; ++k) dst[k] = src[k];
  __syncthreads();
}

// ---------------- fused QKV conv3x3 implicit GEMM ----------------
__global__ __launch_bounds__(256, 2) void conv_qkv(
    const u16* __restrict__ Xin, const u16* __restrict__ Wp,
    const float* __restrict__ qb, const float* __restrict__ kb,
    const float* __restrict__ vb, u16* __restrict__ QP,
    u16* __restrict__ KP, u16* __restrict__ Vout) {
  __shared__ alignas(16) u16 Xs[4 * 66 * 128];
  const int tid = threadIdx.x;
  const int lane = tid & 63;
  const int wv = tid >> 6;
  const int wm = wv >> 1, wn = wv & 1;
  int mt = blockIdx.x;
  mt = (mt & 7) * 64 + (mt >> 3);
  const int b = mt >> 5;
  const int y0 = (mt & 31) * 2;

  stage_tile(Xin, Xs, tid, b, y0);
  __syncthreads();

  f32x4 acc[3][4][4];
#pragma unroll
  for (int c = 0; c < 3; ++c)
#pragma unroll
    for (int i = 0; i < 4; ++i)
#pragma unroll
      for (int j = 0; j < 4; ++j) acc[c][i][j] = f32x4{0.f, 0.f, 0.f, 0.f};

  const int lm = lane & 15, lq = lane >> 4;

#pragma unroll 1
  for (int tap = 0; tap < 9; ++tap) {
    const int dy = (tap * 11) >> 5;  // tap/3
    const int dx = tap - dy * 3;
    const int ysrow = (wm + dy) * 66;
#pragma unroll
    for (int cc = 0; cc < 4; ++cc) {
      const int step = tap * 4 + cc;
      bf16x8 af[4];
#pragma unroll
      for (int i = 0; i < 4; ++i) {
        int xs = i * 16 + lm + dx;
        unsigned off = (unsigned)(((ysrow + xs) * 128 + cc * 32 + lq * 8) * 2) ^
                       (unsigned)((xs & 7) << 4);
        af[i] = *reinterpret_cast<const bf16x8*>(
            reinterpret_cast<const char*>(Xs) + off);
      }
#pragma unroll
      for (int cv = 0; cv < 3; ++cv) {
        const u16* wl = Wp + (size_t)cv * 147456 + (size_t)lane * 8;
        bf16x8 bfr[4];
#pragma unroll
        for (int j = 0; j < 4; ++j)
          bfr[j] = *reinterpret_cast<const bf16x8*>(
              wl + (size_t)((step * 8 + wn * 4 + j) * 64) * 8);
#pragma unroll
        for (int i = 0; i < 4; ++i)
#pragma unroll
          for (int j = 0; j < 4; ++j)
            acc[cv][i][j] = mfma_bf16(af[i], bfr[j], acc[cv][i][j]);
      }
    }
  }

  __syncthreads();  // Xs dead; reuse as epilogue buffer
  epi_pack(acc[0], qb, QP, Xs, tid, wm, wn, lm, lq, b, mt);
  epi_pack(acc[1], kb, KP, Xs, tid, wm, wn, lm, lq, b, mt);
  epi_nat(acc[2], vb, Vout, Xs, tid, wm, wn, lm, lq, mt);
}

// ---------------- conv3x3 implicit GEMM (f1: gelu, f2: f32+residual) ----
// MODE 1: natural bf16 out (+bias, gelu)   [hidden]
// MODE 3: f32 NCHW out (+bias + Fssm add)  [final]
template <int MODE>
__global__ __launch_bounds__(256, 2) void conv_gemm(
    const u16* __restrict__ Xin, const u16* __restrict__ Wp,
    const float* __restrict__ bias, u16* __restrict__ OutB,
    float* __restrict__ OutF, const u16* __restrict__ Fssm) {
  __shared__ alignas(16) u16 Xs[4 * 66 * 128];
  const int tid = threadIdx.x;
  const int lane = tid & 63;
  const int wv = tid >> 6;
  const int wm = wv >> 1, wn = wv & 1;
  int mt = blockIdx.x;
  mt = (mt & 7) * 64 + (mt >> 3);
  const int b = mt >> 5;
  const int y0 = (mt & 31) * 2;

  stage_tile(Xin, Xs, tid, b, y0);
  __syncthreads();

  f32x4 acc[4][4];
#pragma unroll
  for (int i = 0; i < 4; ++i)
#pragma unroll
    for (int j = 0; j < 4; ++j) acc[i][j] = f32x4{0.f, 0.f, 0.f, 0.f};

  const int lm = lane & 15, lq = lane >> 4;
  const u16* wlane = Wp + (size_t)lane * 8;

#pragma unroll
  for (int tap = 0; tap < 9; ++tap) {
    const int dy = tap / 3, dx = tap % 3;
    const int ysrow = (wm + dy) * 66;
#pragma unroll
    for (int cc = 0; cc < 4; ++cc) {
      const int step = tap * 4 + cc;
      bf16x8 af[4], bfr[4];
#pragma unroll
      for (int i = 0; i < 4; ++i) {
        int xs = i * 16 + lm + dx;
        unsigned off = (unsigned)(((ysrow + xs) * 128 + cc * 32 + lq * 8) * 2) ^
                       (unsigned)((xs & 7) << 4);
        af[i] = *reinterpret_cast<const bf16x8*>(
            reinterpret_cast<const char*>(Xs) + off);
      }
#pragma unroll
      for (int j = 0; j < 4; ++j)
        bfr[j] = *reinterpret_cast<const bf16x8*>(
            wlane + (size_t)((step * 8 + wn * 4 + j) * 64) * 8);
#pragma unroll
      for (int i = 0; i < 4; ++i)
#pragma unroll
        for (int j = 0; j < 4; ++j) acc[i][j] = mfma_bf16(af[i], bfr[j], acc[i][j]);
    }
  }

  __syncthreads();

  if (MODE == 1) {
    u16* T = Xs;
#pragma unroll
    for (int i = 0; i < 4; ++i)
#pragma unroll
      for (int j = 0; j < 4; ++j) {
        int n = wn * 64 + j * 16 + lm;
        float bs = bias[n];
#pragma unroll
        for (int r = 0; r < 4; ++r) {
          int m = wm * 64 + i * 16 + lq * 4 + r;
          T[m * 136 + n] = f2bf(gelu_exact(acc[i][j][r] + bs));
        }
      }
    __syncthreads();
    int rr = tid >> 1, hf = tid & 1;
    const uint4* src = reinterpret_cast<const uint4*>(T + rr * 136 + hf * 64);
    uint4* dst = reinterpret_cast<uint4*>(OutB + ((size_t)(mt * 128 + rr) * 128 + hf * 64));
#pragma unroll
    for (int k = 0; k < 8; ++k) dst[k] = src[k];
  } else {
    float* T = reinterpret_cast<float*>(Xs);
#pragma unroll
    for (int i = 0; i < 4; ++i)
#pragma unroll
      for (int j = 0; j < 4; ++j) {
        int n = wn * 64 + j * 16 + lm;
        float bs = bias[n];
#pragma unroll
        for (int r = 0; r < 4; ++r) {
          int m = wm * 64 + i * 16 + lq * 4 + r;
          float v = acc[i][j][r] + bs + bf2f(Fssm[(size_t)(mt * 128 + m) * 128 + n]);
          T[n * 132 + m] = v;
        }
      }
    __syncthreads();
    int rr = tid >> 1, hf = tid & 1;
    const uint4* src = reinterpret_cast<const uint4*>(T + rr * 132 + hf * 64);
    uint4* dst = reinterpret_cast<uint4*>(
        OutF + ((size_t)(b * 128 + rr) * 4096 + (mt & 31) * 128 + hf * 64));
#pragma unroll
    for (int k = 0; k < 16; ++k) dst[k] = src[k];
  }
}

// ---------------- S = K^T Q, split-K=8 -> f32 partials ----------------
__global__ __launch_bounds__(256, 2) void attn_s(const u16* __restrict__ QP,
                                                 const u16* __restrict__ KP,
                                                 float* __restrict__ SP) {
  const int tid = threadIdx.x;
  const int lane = tid & 63;
  const int wv = tid >> 6, wm = wv >> 1, wn = wv & 1;
  const int lm = lane & 15, lq = lane >> 4;
  int mt = blockIdx.x;
  mt = (mt & 7) * 16 + (mt >> 3);  // 128 blocks, bijective XCD swizzle
  const int b = mt >> 3, sp = mt & 7;

  f32x4 acc[4][4];
#pragma unroll
  for (int i = 0; i < 4; ++i)
#pragma unroll
    for (int j = 0; j < 4; ++j) acc[i][j] = f32x4{0.f, 0.f, 0.f, 0.f};

#pragma unroll
  for (int ksl = 0; ksl < 16; ++ksl) {
    const int ks = sp * 16 + ksl;
    bf16x8 af[4], bfr[4];
#pragma unroll
    for (int i = 0; i < 4; ++i)
      af[i] = *reinterpret_cast<const bf16x8*>(
          KP + (size_t)(((b * 128 + ks) * 8 + wm * 4 + i) * 64 + lane) * 8);
#pragma unroll
    for (int j = 0; j < 4; ++j)
      bfr[j] = *reinterpret_cast<const bf16x8*>(
          QP + (size_t)(((b * 128 + ks) * 8 + wn * 4 + j) * 64 + lane) * 8);
#pragma unroll
    for (int i = 0; i < 4; ++i)
#pragma unroll
      for (int j = 0; j < 4; ++j) acc[i][j] = mfma_bf16(af[i], bfr[j], acc[i][j]);
  }

  float* out = SP + (size_t)(b * 8 + sp) * 16384;
#pragma unroll
  for (int i = 0; i < 4; ++i)
#pragma unroll
    for (int j = 0; j < 4; ++j)
#pragma unroll
      for (int r = 0; r < 4; ++r)
        out[(wm * 64 + i * 16 + lq * 4 + r) * 128 + wn * 64 + j * 16 + lm] =
            acc[i][j][r];
}

// ---------------- reduce partials + softmax + pack A ----------------
__global__ __launch_bounds__(256) void attn_r(const float* __restrict__ SP,
                                              u16* __restrict__ ABP) {
  __shared__ float Sf[32][129];
  __shared__ float Inv[32];
  const int tid = threadIdx.x;
  const int b = blockIdx.x >> 2, eb = blockIdx.x & 3;

#pragma unroll
  for (int it = 0; it < 16; ++it) {
    int id = it * 256 + tid;
    int rl = id >> 7, d = id & 127;
    const float* p = SP + (size_t)b * 8 * 16384 + (size_t)(eb * 32 + rl) * 128 + d;
    float s = 0.f;
#pragma unroll
    for (int sp = 0; sp < 8; ++sp) s += p[(size_t)sp * 16384];
    Sf[rl][d] = s * 0.015625f;  // /sqrt(4096)
  }
  __syncthreads();

  {
    int rl = tid >> 3, sub = tid & 7;
    float mx = -3.4e38f;
#pragma unroll
    for (int k = 0; k < 16; ++k) mx = fmaxf(mx, Sf[rl][sub + 8 * k]);
    mx = fmaxf(mx, __shfl_xor(mx, 1));
    mx = fmaxf(mx, __shfl_xor(mx, 2));
    mx = fmaxf(mx, __shfl_xor(mx, 4));
    float s = 0.f;
#pragma unroll
    for (int k = 0; k < 16; ++k) {
      float e = __expf(Sf[rl][sub + 8 * k] - mx);
      Sf[rl][sub + 8 * k] = e;
      s += e;
    }
    s += __shfl_xor(s, 1);
    s += __shfl_xor(s, 2);
    s += __shfl_xor(s, 4);
    if (sub == 0) Inv[rl] = 1.0f / s;
  }
  __syncthreads();

#pragma unroll
  for (int it = 0; it < 2; ++it) {
    int item = tid + it * 256;
    int l = item & 63, nb = item >> 6;
    int d = nb * 16 + (l & 15);
    u16 tmp[8];
#pragma unroll
    for (int e = 0; e < 8; ++e) {
      int rloc = (l >> 4) * 8 + e;
      tmp[e] = f2bf(Sf[rloc][d] * Inv[rloc]);
    }
    *reinterpret_cast<uint4*>(ABP + (size_t)(((b * 4 + eb) * 8 + nb) * 64 + l) * 8) =
        *reinterpret_cast<const uint4*>(tmp);
  }
}

// ---------------- M = Pspe @ A, pack M ----------------
__global__ __launch_bounds__(256, 1) void attn_m(const float* __restrict__ Pspe,
                                                 const u16* __restrict__ ABP,
                                                 u16* __restrict__ Mpack) {
  __shared__ u16 Ml[128 * 136];
  const int b = blockIdx.x;
  const int tid = threadIdx.x;
  const int lane = tid & 63;
  const int wv = tid >> 6, wm = wv >> 1, wn = wv & 1;
  const int lm = lane & 15, lq = lane >> 4;

  f32x4 acc[4][4];
#pragma unroll
  for (int i = 0; i < 4; ++i)
#pragma unroll
    for (int j = 0; j < 4; ++j) acc[i][j] = f32x4{0.f, 0.f, 0.f, 0.f};

  const float* P = Pspe + (size_t)b * 128 * 128;
#pragma unroll
  for (int cc = 0; cc < 4; ++cc) {
    int e0 = cc * 32 + lq * 8;
    bf16x8 af[4], bfr[4];
#pragma unroll
    for (int i = 0; i < 4; ++i) {
      const float* p = P + (size_t)(wm * 64 + i * 16 + lm) * 128 + e0;
      union { u16 u[8]; bf16x8 v; } cv;
#pragma unroll
      for (int e = 0; e < 8; ++e) cv.u[e] = f2bf(p[e]);
      af[i] = cv.v;
    }
#pragma unroll
    for (int j = 0; j < 4; ++j)
      bfr[j] = *reinterpret_cast<const bf16x8*>(
          ABP + (size_t)(((b * 4 + cc) * 8 + wn * 4 + j) * 64 + lane) * 8);
#pragma unroll
    for (int i = 0; i < 4; ++i)
#pragma unroll
      for (int j = 0; j < 4; ++j) acc[i][j] = mfma_bf16(af[i], bfr[j], acc[i][j]);
  }

#pragma unroll
  for (int i = 0; i < 4; ++i)
#pragma unroll
    for (int j = 0; j < 4; ++j)
#pragma unroll
      for (int r = 0; r < 4; ++r)
        Ml[(wn * 64 + j * 16 + lm) * 136 + (wm * 64 + i * 16 + lq * 4 + r)] =
            f2bf(acc[i][j][r]);
  __syncthreads();

#pragma unroll
  for (int it = 0; it < 8; ++it) {
    int item = tid + it * 256;
    int l2 = item & 63, nb = (item >> 6) & 7, cc2 = item >> 9;
    int d = nb * 16 + (l2 & 15), c0 = cc2 * 32 + (l2 >> 4) * 8;
    *reinterpret_cast<uint4*>(Mpack + (size_t)b * 16384 + (size_t)item * 8) =
        *reinterpret_cast<const uint4*>(Ml + d * 136 + c0);
  }
}

// ---------------- F3 = V @ M -> Fssm (NHWC bf16) ----------------
__global__ __launch_bounds__(256) void f3_gemm(const u16* __restrict__ V,
                                               const u16* __restrict__ Mpack,
                                               u16* __restrict__ Fout) {
  const int tid = threadIdx.x;
  const int lane = tid & 63;
  const int wv = tid >> 6, wm = wv >> 1, wn = wv & 1;
  const int lm = lane & 15, lq = lane >> 4;
  int mt = blockIdx.x;
  mt = (mt & 7) * 64 + (mt >> 3);
  const int b = mt >> 5;

  f32x4 acc[4][4];
#pragma unroll
  for (int i = 0; i < 4; ++i)
#pragma unroll
    for (int j = 0; j < 4; ++j) acc[i][j] = f32x4{0.f, 0.f, 0.f, 0.f};

#pragma unroll
  for (int cc = 0; cc < 4; ++cc) {
    int k0 = cc * 32 + lq * 8;
    bf16x8 af[4], bfr[4];
#pragma unroll
    for (int i = 0; i < 4; ++i)
      af[i] = *reinterpret_cast<const bf16x8*>(
          V + (size_t)(mt * 128 + wm * 64 + i * 16 + lm) * 128 + k0);
#pragma unroll
    for (int j = 0; j < 4; ++j)
      bfr[j] = *reinterpret_cast<const bf16x8*>(
          Mpack + (size_t)b * 16384 + (size_t)((cc * 8 + wn * 4 + j) * 64 + lane) * 8);
#pragma unroll
    for (int i = 0; i < 4; ++i)
#pragma unroll
      for (int j = 0; j < 4; ++j) acc[i][j] = mfma_bf16(af[i], bfr[j], acc[i][j]);
  }

  __shared__ u16 T[128 * 136];
#pragma unroll
  for (int i = 0; i < 4; ++i)
#pragma unroll
    for (int j = 0; j < 4; ++j)
#pragma unroll
      for (int r = 0; r < 4; ++r)
        T[(wm * 64 + i * 16 + lq * 4 + r) * 136 + wn * 64 + j * 16 + lm] =
            f2bf(acc[i][j][r]);
  __syncthreads();
  int rr = tid >> 1, hf = tid & 1;
  const uint4* src = reinterpret_cast<const uint4*>(T + rr * 136 + hf * 64);
  uint4* dst = reinterpret_cast<uint4*>(Fout + ((size_t)(mt * 128 + rr) * 128 + hf * 64));
#pragma unroll
  for (int k = 0; k < 8; ++k) dst[k] = src[k];
}

extern "C" void kernel_launch(void* const* d_in, const int* in_sizes, int n_in,
                              void* d_out, int out_size, void* d_ws, size_t ws_size,
                              hipStream_t stream) {
  const float* F_in = (const float*)d_in[0];
  const float* Pspe = (const float*)d_in[1];
  const float* q_w = (const float*)d_in[2];
  const float* q_b = (const float*)d_in[3];
  const float* k_w = (const float*)d_in[4];
  const float* k_b = (const float*)d_in[5];
  const float* v_w = (const float*)d_in[6];
  const float* v_b = (const float*)d_in[7];
  const float* f1_w = (const float*)d_in[8];
  const float* f1_b = (const float*)d_in[9];
  const float* f2_w = (const float*)d_in[10];
  const float* f2_b = (const float*)d_in[11];
  float* out = (float*)d_out;

  char* ws = (char*)d_ws;
  const size_t SZ = 16777216;  // 65536*128*2 bytes
  u16* X = (u16*)(ws);                  // NHWC bf16 input
  u16* QP = (u16*)(ws + SZ);            // fragment-packed Q; later hidden
  u16* KP = (u16*)(ws + 2 * SZ);        // fragment-packed K; later ABP
  u16* V = (u16*)(ws + 3 * SZ);
  u16* Wpk = (u16*)(ws + 4 * SZ);
  u16* Mpk = (u16*)(ws + 4 * SZ + 1474560);
  float* SP = (float*)ws;               // 8.4 MB partials — aliases X
  u16* ABP = KP;
  u16* Fssm = X;
  u16* Hid = QP;

  pack_x<<<1024, 256, 0, stream>>>(F_in, X);
  pack_w<<<360, 256, 0, stream>>>(q_w, k_w, v_w, f1_w, f2_w, Wpk);
  conv_qkv<<<512, 256, 0, stream>>>(X, Wpk, q_b, k_b, v_b, QP, KP, V);
  attn_s<<<128, 256, 0, stream>>>(QP, KP, SP);
  attn_r<<<64, 256, 0, stream>>>(SP, ABP);
  attn_m<<<16, 256, 0, stream>>>(Pspe, ABP, Mpk);
  f3_gemm<<<512, 256, 0, stream>>>(V, Mpk, Fssm);
  conv_gemm<1><<<512, 256, 0, stream>>>(Fssm, Wpk + 3 * 147456, f1_b, Hid, nullptr, nullptr);
  conv_gemm<3><<<512, 256, 0, stream>>>(Hid, Wpk + 4 * 147456, f2_b, nullptr, out, Fssm);
}

// Round 4
// 176.856 us; speedup vs baseline: 1.8057x; 1.0311x over previous
//
#include <hip/hip_runtime.h>
#include <cmath>

typedef unsigned short u16;
typedef __bf16 bf16x8 __attribute__((ext_vector_type(8)));
typedef float f32x4 __attribute__((ext_vector_type(4)));

__device__ __forceinline__ u16 f2bf(float f) {
  unsigned u = __float_as_uint(f);
  u += 0x7fffu + ((u >> 16) & 1u);
  return (u16)(u >> 16);
}
__device__ __forceinline__ float bf2f(u16 h) {
  return __uint_as_float(((unsigned)h) << 16);
}
__device__ __forceinline__ f32x4 mfma_bf16(bf16x8 a, bf16x8 b, f32x4 c) {
  return __builtin_amdgcn_mfma_f32_16x16x32_bf16(a, b, c, 0, 0, 0);
}
__device__ __forceinline__ float gelu_exact(float x) {
  return 0.5f * x * (1.0f + erff(x * 0.70710678118654752440f));
}

// B=16, C=128, H=64, W=64, HW=4096, NPOS=65536

// ---------------- merged pack: X (NCHW f32 -> NHWC bf16) + weights ----------
__global__ __launch_bounds__(256) void pack_xw(
    const float* __restrict__ Fin, u16* __restrict__ X,
    const float* __restrict__ w0, const float* __restrict__ w1,
    const float* __restrict__ w2, const float* __restrict__ w3,
    const float* __restrict__ w4, u16* __restrict__ Wpk) {
  __shared__ float T[64 * 129];
  const int tid = threadIdx.x;
  if (blockIdx.x < 1024) {
    const int b = blockIdx.x >> 6, y = blockIdx.x & 63;
#pragma unroll
    for (int i = 0; i < 32; ++i) {
      int idx = tid + i * 256;
      int c = idx >> 6, x = idx & 63;
      T[x * 129 + c] = Fin[(size_t)(b * 128 + c) * 4096 + y * 64 + x];
    }
    __syncthreads();
#pragma unroll
    for (int i = 0; i < 4; ++i) {
      int chunk = tid + i * 256;
      int x = chunk >> 4;
      int c0 = (chunk & 15) * 8;
      u16 tmp[8];
#pragma unroll
      for (int e = 0; e < 8; ++e) tmp[e] = f2bf(T[x * 129 + c0 + e]);
      *reinterpret_cast<uint4*>(X + ((size_t)((b * 64 + y) * 64 + x) * 128 + c0)) =
          *reinterpret_cast<const uint4*>(tmp);
    }
  } else {
    int gid = (blockIdx.x - 1024) * 256 + tid;  // 92160 total
    int lane = gid & 63;
    int nblk = (gid >> 6) & 7;
    int step = (gid >> 9) % 36;
    int conv = gid / (512 * 36);
    if (conv >= 5) return;
    const float* w = conv == 0 ? w0 : conv == 1 ? w1 : conv == 2 ? w2 : conv == 3 ? w3 : w4;
    int tap = step >> 2, cc = step & 3;
    int dy = tap / 3, dx = tap % 3;
    int co = nblk * 16 + (lane & 15);
    int ci0 = cc * 32 + (lane >> 4) * 8;
    u16 tmp[8];
#pragma unroll
    for (int e = 0; e < 8; ++e)
      tmp[e] = f2bf(w[((size_t)(co * 128 + ci0 + e) * 3 + dy) * 3 + dx]);
    size_t off = ((size_t)conv * 36 * 8 * 64 + (size_t)((step * 8 + nblk) * 64 + lane)) * 8;
    *reinterpret_cast<uint4*>(Wpk + off) = *reinterpret_cast<const uint4*>(tmp);
  }
}

// ======== shared staging: rows y0-1..y0+2, x-halo, XOR-swizzled ========
__device__ __forceinline__ void stage_tile(const u16* __restrict__ Xin, u16* Xs,
                                           int tid, int b, int y0) {
#pragma unroll
  for (int i = 0; i < 16; ++i) {
    int j = tid + i * 256;
    int row = j >> 4;
    int c16 = j & 15;
    int ys = row >> 6, x = row & 63;
    int ysrc = y0 - 1 + ys;
    uint4 val = make_uint4(0u, 0u, 0u, 0u);
    if ((unsigned)ysrc < 64u)
      val = *reinterpret_cast<const uint4*>(
          Xin + ((size_t)((b * 64 + ysrc) * 64 + x) * 128 + c16 * 8));
    int xs = x + 1;
    unsigned off = (unsigned)(((ys * 66 + xs) * 128 + c16 * 8) * 2) ^
                   (unsigned)((xs & 7) << 4);
    *reinterpret_cast<uint4*>(reinterpret_cast<char*>(Xs) + off) = val;
  }
  if (tid < 128) {
    int ys = tid >> 5, side = (tid >> 4) & 1, c16 = tid & 15;
    int xs = side ? 65 : 0;
    unsigned off = (unsigned)(((ys * 66 + xs) * 128 + c16 * 8) * 2) ^
                   (unsigned)((xs & 7) << 4);
    *reinterpret_cast<uint4*>(reinterpret_cast<char*>(Xs) + off) =
        make_uint4(0u, 0u, 0u, 0u);
  }
}

// ---------------- fused QKV conv3x3, N-split tile M128xN64, pipelined -------
__global__ __launch_bounds__(256, 2) void conv_qkv(
    const u16* __restrict__ Xin, const u16* __restrict__ Wp,
    const float* __restrict__ qb, const float* __restrict__ kb,
    const float* __restrict__ vb, u16* __restrict__ QP,
    u16* __restrict__ KP, u16* __restrict__ Vout) {
  __shared__ alignas(16) u16 Xs[4 * 66 * 128];
  const int tid = threadIdx.x;
  const int lane = tid & 63;
  const int wv = tid >> 6;
  const int wm = wv >> 1, wn = wv & 1;
  int mt = blockIdx.x;
  mt = (mt & 7) * 128 + (mt >> 3);  // 1024 blocks, bijective XCD swizzle
  const int b = mt >> 6;
  const int r = mt & 63;
  const int yp = r >> 1;      // y-pair 0..31
  const int nh = r & 1;       // N half
  const int y0 = yp * 2;

  stage_tile(Xin, Xs, tid, b, y0);
  __syncthreads();

  f32x4 acc[3][4][2];
#pragma unroll
  for (int c = 0; c < 3; ++c)
#pragma unroll
    for (int i = 0; i < 4; ++i)
#pragma unroll
      for (int j = 0; j < 2; ++j) acc[c][i][j] = f32x4{0.f, 0.f, 0.f, 0.f};

  const int lm = lane & 15, lq = lane >> 4;
  const u16* wb = Wp + (size_t)(((nh * 4 + wn * 2) * 64) + lane) * 8;

  auto loada = [&](bf16x8 (&d)[4], int s) {
    int tap = s >> 2, cc = s & 3;
    int dy = (tap * 11) >> 5;
    int dx = tap - dy * 3;
    int row = (wm + dy) * 66;
#pragma unroll
    for (int i = 0; i < 4; ++i) {
      int xs = i * 16 + lm + dx;
      unsigned off = (unsigned)(((row + xs) * 128 + cc * 32 + lq * 8) * 2) ^
                     (unsigned)((xs & 7) << 4);
      d[i] = *reinterpret_cast<const bf16x8*>(reinterpret_cast<const char*>(Xs) + off);
    }
  };
  auto loadb = [&](bf16x8 (&d)[6], int s) {
#pragma unroll
    for (int cv = 0; cv < 3; ++cv)
#pragma unroll
      for (int j = 0; j < 2; ++j)
        d[cv * 2 + j] = *reinterpret_cast<const bf16x8*>(
            wb + (size_t)cv * 147456 + (size_t)s * 4096 + j * 512);
  };
  auto step = [&](bf16x8 (&a)[4], bf16x8 (&bm)[6]) {
#pragma unroll
    for (int cv = 0; cv < 3; ++cv)
#pragma unroll
      for (int i = 0; i < 4; ++i)
#pragma unroll
        for (int j = 0; j < 2; ++j)
          acc[cv][i][j] = mfma_bf16(a[i], bm[cv * 2 + j], acc[cv][i][j]);
  };

  bf16x8 a0[4], a1[4], b0[6], b1[6];
  loada(a0, 0);
  loadb(b0, 0);
#pragma unroll 1
  for (int s = 0; s < 36; s += 2) {
    loada(a1, s + 1);
    loadb(b1, s + 1);
    step(a0, b0);
    if (s + 2 < 36) {
      loada(a0, s + 2);
      loadb(b0, s + 2);
    }
    step(a1, b1);
  }

  __syncthreads();  // Xs dead; reuse for epilogues

  // ---- Q, K: fragment-packed epilogue ----
  u16* T = Xs;  // [64][136]
#pragma unroll
  for (int cv = 0; cv < 2; ++cv) {
    const float* bias = cv == 0 ? qb : kb;
    u16* OutB = cv == 0 ? QP : KP;
#pragma unroll
    for (int i = 0; i < 4; ++i)
#pragma unroll
      for (int j = 0; j < 2; ++j) {
        int nloc = wn * 32 + j * 16 + lm;
        float bs = bias[nh * 64 + nloc];
#pragma unroll
        for (int rr = 0; rr < 4; ++rr) {
          int m = wm * 64 + i * 16 + lq * 4 + rr;
          T[nloc * 136 + m] = f2bf(acc[cv][i][j][rr] + bs);
        }
      }
    __syncthreads();
#pragma unroll
    for (int it = 0; it < 4; ++it) {
      int item = tid + it * 256;  // 0..1023
      int l = item & 63, cbl = (item >> 6) & 3, ksl = item >> 8;
      int c = cbl * 16 + (l & 15);
      int mloc = ksl * 32 + (l >> 4) * 8;
      int ks = yp * 4 + ksl, cb = nh * 4 + cbl;
      *reinterpret_cast<uint4*>(
          OutB + (size_t)(((b * 128 + ks) * 8 + cb) * 64 + l) * 8) =
          *reinterpret_cast<const uint4*>(T + c * 136 + mloc);
    }
    __syncthreads();
  }

  // ---- V: natural [pos][ch] ----
  u16* Tv = Xs;  // [128][72]
#pragma unroll
  for (int i = 0; i < 4; ++i)
#pragma unroll
    for (int j = 0; j < 2; ++j) {
      int nloc = wn * 32 + j * 16 + lm;
      float bs = vb[nh * 64 + nloc];
#pragma unroll
      for (int rr = 0; rr < 4; ++rr) {
        int m = wm * 64 + i * 16 + lq * 4 + rr;
        Tv[m * 72 + nloc] = f2bf(acc[2][i][j][rr] + bs);
      }
    }
  __syncthreads();
  {
    int rr = tid >> 1, q = tid & 1;
    const uint4* src = reinterpret_cast<const uint4*>(Tv + rr * 72 + q * 32);
    uint4* dst = reinterpret_cast<uint4*>(
        Vout + ((size_t)((b * 32 + yp) * 128 + rr) * 128 + nh * 64 + q * 32));
#pragma unroll
    for (int k = 0; k < 4; ++k) dst[k] = src[k];
  }
}

// ---------------- conv3x3 implicit GEMM (f1: gelu, f2: f32+residual), pipelined
// MODE 1: natural bf16 out (+bias, gelu)   [hidden]
// MODE 3: f32 NCHW out (+bias + Fssm add)  [final]
template <int MODE>
__global__ __launch_bounds__(256, 2) void conv_gemm(
    const u16* __restrict__ Xin, const u16* __restrict__ Wp,
    const float* __restrict__ bias, u16* __restrict__ OutB,
    float* __restrict__ OutF, const u16* __restrict__ Fssm) {
  __shared__ alignas(16) u16 Xs[4 * 66 * 128];
  const int tid = threadIdx.x;
  const int lane = tid & 63;
  const int wv = tid >> 6;
  const int wm = wv >> 1, wn = wv & 1;
  int mt = blockIdx.x;
  mt = (mt & 7) * 64 + (mt >> 3);
  const int b = mt >> 5;
  const int y0 = (mt & 31) * 2;

  stage_tile(Xin, Xs, tid, b, y0);
  __syncthreads();

  f32x4 acc[4][4];
#pragma unroll
  for (int i = 0; i < 4; ++i)
#pragma unroll
    for (int j = 0; j < 4; ++j) acc[i][j] = f32x4{0.f, 0.f, 0.f, 0.f};

  const int lm = lane & 15, lq = lane >> 4;
  const u16* wb = Wp + (size_t)((wn * 4 * 64) + lane) * 8;

  auto loada = [&](bf16x8 (&d)[4], int s) {
    int tap = s >> 2, cc = s & 3;
    int dy = (tap * 11) >> 5;
    int dx = tap - dy * 3;
    int row = (wm + dy) * 66;
#pragma unroll
    for (int i = 0; i < 4; ++i) {
      int xs = i * 16 + lm + dx;
      unsigned off = (unsigned)(((row + xs) * 128 + cc * 32 + lq * 8) * 2) ^
                     (unsigned)((xs & 7) << 4);
      d[i] = *reinterpret_cast<const bf16x8*>(reinterpret_cast<const char*>(Xs) + off);
    }
  };
  auto loadb = [&](bf16x8 (&d)[4], int s) {
#pragma unroll
    for (int j = 0; j < 4; ++j)
      d[j] = *reinterpret_cast<const bf16x8*>(wb + (size_t)s * 4096 + j * 512);
  };
  auto step = [&](bf16x8 (&a)[4], bf16x8 (&bm)[4]) {
#pragma unroll
    for (int i = 0; i < 4; ++i)
#pragma unroll
      for (int j = 0; j < 4; ++j) acc[i][j] = mfma_bf16(a[i], bm[j], acc[i][j]);
  };

  bf16x8 a0[4], a1[4], b0[4], b1[4];
  loada(a0, 0);
  loadb(b0, 0);
#pragma unroll 1
  for (int s = 0; s < 36; s += 2) {
    loada(a1, s + 1);
    loadb(b1, s + 1);
    step(a0, b0);
    if (s + 2 < 36) {
      loada(a0, s + 2);
      loadb(b0, s + 2);
    }
    step(a1, b1);
  }

  __syncthreads();

  if (MODE == 1) {
    u16* T = Xs;
#pragma unroll
    for (int i = 0; i < 4; ++i)
#pragma unroll
      for (int j = 0; j < 4; ++j) {
        int n = wn * 64 + j * 16 + lm;
        float bs = bias[n];
#pragma unroll
        for (int r = 0; r < 4; ++r) {
          int m = wm * 64 + i * 16 + lq * 4 + r;
          T[m * 136 + n] = f2bf(gelu_exact(acc[i][j][r] + bs));
        }
      }
    __syncthreads();
    int rr = tid >> 1, hf = tid & 1;
    const uint4* src = reinterpret_cast<const uint4*>(T + rr * 136 + hf * 64);
    uint4* dst = reinterpret_cast<uint4*>(OutB + ((size_t)(mt * 128 + rr) * 128 + hf * 64));
#pragma unroll
    for (int k = 0; k < 8; ++k) dst[k] = src[k];
  } else {
    float* T = reinterpret_cast<float*>(Xs);
#pragma unroll
    for (int i = 0; i < 4; ++i)
#pragma unroll
      for (int j = 0; j < 4; ++j) {
        int n = wn * 64 + j * 16 + lm;
        float bs = bias[n];
#pragma unroll
        for (int r = 0; r < 4; ++r) {
          int m = wm * 64 + i * 16 + lq * 4 + r;
          float v = acc[i][j][r] + bs + bf2f(Fssm[(size_t)(mt * 128 + m) * 128 + n]);
          T[n * 132 + m] = v;
        }
      }
    __syncthreads();
    int rr = tid >> 1, hf = tid & 1;
    const uint4* src = reinterpret_cast<const uint4*>(T + rr * 132 + hf * 64);
    uint4* dst = reinterpret_cast<uint4*>(
        OutF + ((size_t)(b * 128 + rr) * 4096 + (mt & 31) * 128 + hf * 64));
#pragma unroll
    for (int k = 0; k < 16; ++k) dst[k] = src[k];
  }
}

// ---------------- S = K^T Q, split-K=8 -> f32 partials ----------------
__global__ __launch_bounds__(256, 2) void attn_s(const u16* __restrict__ QP,
                                                 const u16* __restrict__ KP,
                                                 float* __restrict__ SP) {
  const int tid = threadIdx.x;
  const int lane = tid & 63;
  const int wv = tid >> 6, wm = wv >> 1, wn = wv & 1;
  const int lm = lane & 15, lq = lane >> 4;
  int mt = blockIdx.x;
  mt = (mt & 7) * 16 + (mt >> 3);  // 128 blocks, bijective
  const int b = mt >> 3, sp = mt & 7;

  f32x4 acc[4][4];
#pragma unroll
  for (int i = 0; i < 4; ++i)
#pragma unroll
    for (int j = 0; j < 4; ++j) acc[i][j] = f32x4{0.f, 0.f, 0.f, 0.f};

#pragma unroll
  for (int ksl = 0; ksl < 16; ++ksl) {
    const int ks = sp * 16 + ksl;
    bf16x8 af[4], bfr[4];
#pragma unroll
    for (int i = 0; i < 4; ++i)
      af[i] = *reinterpret_cast<const bf16x8*>(
          KP + (size_t)(((b * 128 + ks) * 8 + wm * 4 + i) * 64 + lane) * 8);
#pragma unroll
    for (int j = 0; j < 4; ++j)
      bfr[j] = *reinterpret_cast<const bf16x8*>(
          QP + (size_t)(((b * 128 + ks) * 8 + wn * 4 + j) * 64 + lane) * 8);
#pragma unroll
    for (int i = 0; i < 4; ++i)
#pragma unroll
      for (int j = 0; j < 4; ++j) acc[i][j] = mfma_bf16(af[i], bfr[j], acc[i][j]);
  }

  float* out = SP + (size_t)(b * 8 + sp) * 16384;
#pragma unroll
  for (int i = 0; i < 4; ++i)
#pragma unroll
    for (int j = 0; j < 4; ++j)
#pragma unroll
      for (int r = 0; r < 4; ++r)
        out[(wm * 64 + i * 16 + lq * 4 + r) * 128 + wn * 64 + j * 16 + lm] =
            acc[i][j][r];
}

// ---------------- reduce partials + softmax + pack A ----------------
__global__ __launch_bounds__(256) void attn_r(const float* __restrict__ SP,
                                              u16* __restrict__ ABP) {
  __shared__ float Sf[32][129];
  __shared__ float Inv[32];
  const int tid = threadIdx.x;
  const int b = blockIdx.x >> 2, eb = blockIdx.x & 3;

#pragma unroll
  for (int it = 0; it < 16; ++it) {
    int id = it * 256 + tid;
    int rl = id >> 7, d = id & 127;
    const float* p = SP + (size_t)b * 8 * 16384 + (size_t)(eb * 32 + rl) * 128 + d;
    float s = 0.f;
#pragma unroll
    for (int sp = 0; sp < 8; ++sp) s += p[(size_t)sp * 16384];
    Sf[rl][d] = s * 0.015625f;
  }
  __syncthreads();

  {
    int rl = tid >> 3, sub = tid & 7;
    float mx = -3.4e38f;
#pragma unroll
    for (int k = 0; k < 16; ++k) mx = fmaxf(mx, Sf[rl][sub + 8 * k]);
    mx = fmaxf(mx, __shfl_xor(mx, 1));
    mx = fmaxf(mx, __shfl_xor(mx, 2));
    mx = fmaxf(mx, __shfl_xor(mx, 4));
    float s = 0.f;
#pragma unroll
    for (int k = 0; k < 16; ++k) {
      float e = __expf(Sf[rl][sub + 8 * k] - mx);
      Sf[rl][sub + 8 * k] = e;
      s += e;
    }
    s += __shfl_xor(s, 1);
    s += __shfl_xor(s, 2);
    s += __shfl_xor(s, 4);
    if (sub == 0) Inv[rl] = 1.0f / s;
  }
  __syncthreads();

#pragma unroll
  for (int it = 0; it < 2; ++it) {
    int item = tid + it * 256;
    int l = item & 63, nb = item >> 6;
    int d = nb * 16 + (l & 15);
    u16 tmp[8];
#pragma unroll
    for (int e = 0; e < 8; ++e) {
      int rloc = (l >> 4) * 8 + e;
      tmp[e] = f2bf(Sf[rloc][d] * Inv[rloc]);
    }
    *reinterpret_cast<uint4*>(ABP + (size_t)(((b * 4 + eb) * 8 + nb) * 64 + l) * 8) =
        *reinterpret_cast<const uint4*>(tmp);
  }
}

// ---------------- M = Pspe @ A, pack M ----------------
__global__ __launch_bounds__(256, 1) void attn_m(const float* __restrict__ Pspe,
                                                 const u16* __restrict__ ABP,
                                                 u16* __restrict__ Mpack) {
  __shared__ u16 Ml[128 * 136];
  const int b = blockIdx.x;
  const int tid = threadIdx.x;
  const int lane = tid & 63;
  const int wv = tid >> 6, wm = wv >> 1, wn = wv & 1;
  const int lm = lane & 15, lq = lane >> 4;

  f32x4 acc[4][4];
#pragma unroll
  for (int i = 0; i < 4; ++i)
#pragma unroll
    for (int j = 0; j < 4; ++j) acc[i][j] = f32x4{0.f, 0.f, 0.f, 0.f};

  const float* P = Pspe + (size_t)b * 128 * 128;
#pragma unroll
  for (int cc = 0; cc < 4; ++cc) {
    int e0 = cc * 32 + lq * 8;
    bf16x8 af[4], bfr[4];
#pragma unroll
    for (int i = 0; i < 4; ++i) {
      const float* p = P + (size_t)(wm * 64 + i * 16 + lm) * 128 + e0;
      union { u16 u[8]; bf16x8 v; } cv;
#pragma unroll
      for (int e = 0; e < 8; ++e) cv.u[e] = f2bf(p[e]);
      af[i] = cv.v;
    }
#pragma unroll
    for (int j = 0; j < 4; ++j)
      bfr[j] = *reinterpret_cast<const bf16x8*>(
          ABP + (size_t)(((b * 4 + cc) * 8 + wn * 4 + j) * 64 + lane) * 8);
#pragma unroll
    for (int i = 0; i < 4; ++i)
#pragma unroll
      for (int j = 0; j < 4; ++j) acc[i][j] = mfma_bf16(af[i], bfr[j], acc[i][j]);
  }

#pragma unroll
  for (int i = 0; i < 4; ++i)
#pragma unroll
    for (int j = 0; j < 4; ++j)
#pragma unroll
      for (int r = 0; r < 4; ++r)
        Ml[(wn * 64 + j * 16 + lm) * 136 + (wm * 64 + i * 16 + lq * 4 + r)] =
            f2bf(acc[i][j][r]);
  __syncthreads();

#pragma unroll
  for (int it = 0; it < 8; ++it) {
    int item = tid + it * 256;
    int l2 = item & 63, nb = (item >> 6) & 7, cc2 = item >> 9;
    int d = nb * 16 + (l2 & 15), c0 = cc2 * 32 + (l2 >> 4) * 8;
    *reinterpret_cast<uint4*>(Mpack + (size_t)b * 16384 + (size_t)item * 8) =
        *reinterpret_cast<const uint4*>(Ml + d * 136 + c0);
  }
}

// ---------------- F3 = V @ M -> Fssm (NHWC bf16) ----------------
__global__ __launch_bounds__(256) void f3_gemm(const u16* __restrict__ V,
                                               const u16* __restrict__ Mpack,
                                               u16* __restrict__ Fout) {
  const int tid = threadIdx.x;
  const int lane = tid & 63;
  const int wv = tid >> 6, wm = wv >> 1, wn = wv & 1;
  const int lm = lane & 15, lq = lane >> 4;
  int mt = blockIdx.x;
  mt = (mt & 7) * 64 + (mt >> 3);
  const int b = mt >> 5;

  f32x4 acc[4][4];
#pragma unroll
  for (int i = 0; i < 4; ++i)
#pragma unroll
    for (int j = 0; j < 4; ++j) acc[i][j] = f32x4{0.f, 0.f, 0.f, 0.f};

#pragma unroll
  for (int cc = 0; cc < 4; ++cc) {
    int k0 = cc * 32 + lq * 8;
    bf16x8 af[4], bfr[4];
#pragma unroll
    for (int i = 0; i < 4; ++i)
      af[i] = *reinterpret_cast<const bf16x8*>(
          V + (size_t)(mt * 128 + wm * 64 + i * 16 + lm) * 128 + k0);
#pragma unroll
    for (int j = 0; j < 4; ++j)
      bfr[j] = *reinterpret_cast<const bf16x8*>(
          Mpack + (size_t)b * 16384 + (size_t)((cc * 8 + wn * 4 + j) * 64 + lane) * 8);
#pragma unroll
    for (int i = 0; i < 4; ++i)
#pragma unroll
      for (int j = 0; j < 4; ++j) acc[i][j] = mfma_bf16(af[i], bfr[j], acc[i][j]);
  }

  __shared__ u16 T[128 * 136];
#pragma unroll
  for (int i = 0; i < 4; ++i)
#pragma unroll
    for (int j = 0; j < 4; ++j)
#pragma unroll
      for (int r = 0; r < 4; ++r)
        T[(wm * 64 + i * 16 + lq * 4 + r) * 136 + wn * 64 + j * 16 + lm] =
            f2bf(acc[i][j][r]);
  __syncthreads();
  int rr = tid >> 1, hf = tid & 1;
  const uint4* src = reinterpret_cast<const uint4*>(T + rr * 136 + hf * 64);
  uint4* dst = reinterpret_cast<uint4*>(Fout + ((size_t)(mt * 128 + rr) * 128 + hf * 64));
#pragma unroll
  for (int k = 0; k < 8; ++k) dst[k] = src[k];
}

extern "C" void kernel_launch(void* const* d_in, const int* in_sizes, int n_in,
                              void* d_out, int out_size, void* d_ws, size_t ws_size,
                              hipStream_t stream) {
  const float* F_in = (const float*)d_in[0];
  const float* Pspe = (const float*)d_in[1];
  const float* q_w = (const float*)d_in[2];
  const float* q_b = (const float*)d_in[3];
  const float* k_w = (const float*)d_in[4];
  const float* k_b = (const float*)d_in[5];
  const float* v_w = (const float*)d_in[6];
  const float* v_b = (const float*)d_in[7];
  const float* f1_w = (const float*)d_in[8];
  const float* f1_b = (const float*)d_in[9];
  const float* f2_w = (const float*)d_in[10];
  const float* f2_b = (const float*)d_in[11];
  float* out = (float*)d_out;

  char* ws = (char*)d_ws;
  const size_t SZ = 16777216;  // 65536*128*2 bytes
  u16* X = (u16*)(ws);
  u16* QP = (u16*)(ws + SZ);
  u16* KP = (u16*)(ws + 2 * SZ);
  u16* V = (u16*)(ws + 3 * SZ);
  u16* Wpk = (u16*)(ws + 4 * SZ);
  u16* Mpk = (u16*)(ws + 4 * SZ + 1474560);
  float* SP = (float*)ws;  // aliases X (dead by then)
  u16* ABP = KP;
  u16* Fssm = X;
  u16* Hid = QP;

  pack_xw<<<1384, 256, 0, stream>>>(F_in, X, q_w, k_w, v_w, f1_w, f2_w, Wpk);
  conv_qkv<<<1024, 256, 0, stream>>>(X, Wpk, q_b, k_b, v_b, QP, KP, V);
  attn_s<<<128, 256, 0, stream>>>(QP, KP, SP);
  attn_r<<<64, 256, 0, stream>>>(SP, ABP);
  attn_m<<<16, 256, 0, stream>>>(Pspe, ABP, Mpk);
  f3_gemm<<<512, 256, 0, stream>>>(V, Mpk, Fssm);
  conv_gemm<1><<<512, 256, 0, stream>>>(Fssm, Wpk + 3 * 147456, f1_b, Hid, nullptr, nullptr);
  conv_gemm<3><<<512, 256, 0, stream>>>(Hid, Wpk + 4 * 147456, f2_b, nullptr, out, Fssm);
}